// Round 5
// baseline (1583.991 us; speedup 1.0000x reference)
//
#include <hip/hip_runtime.h>

#define NB 32       // B
#define NT 512      // T
#define ND 2048     // D
#define NDM 256     // DM
#define NDI 512     // DI
#define NDS 16      // DS
#define NR 16       // R
#define NH 128      // H
#define NNC 8       // NC
#define NL 4        // L
#define NM (NB*NT)  // 16384 tokens

typedef __attribute__((ext_vector_type(8))) short short8;
typedef __attribute__((ext_vector_type(4))) float floatx4;

__device__ __forceinline__ unsigned short f2bf_rn(float f) {
    unsigned u = __builtin_bit_cast(unsigned, f);
    u += 0x7FFFu + ((u >> 16) & 1u);
    return (unsigned short)(u >> 16);
}
__device__ __forceinline__ void cvt8(const float* v, short8& h8, short8& l8) {
#pragma unroll
    for (int q = 0; q < 8; ++q) {
        unsigned short hb = f2bf_rn(v[q]);
        float hf = __builtin_bit_cast(float, (unsigned)hb << 16);
        h8[q] = (short)hb;
        l8[q] = (short)f2bf_rn(v[q] - hf);
    }
}
// sum over the 4 lanes of a quad via DPP (VALU pipe, no LDS)
__device__ __forceinline__ float quad_sum(float v) {
    int i = __builtin_bit_cast(int, v);
    int j = __builtin_amdgcn_update_dpp(0, i, 0xB1, 0xF, 0xF, true); // quad xor1
    v += __builtin_bit_cast(float, j);
    i = __builtin_bit_cast(int, v);
    j = __builtin_amdgcn_update_dpp(0, i, 0x4E, 0xF, 0xF, true);     // quad xor2
    v += __builtin_bit_cast(float, j);
    return v;
}
// async global->LDS, 16B per lane; lds base must be wave-uniform (HW adds lane*16)
__device__ __forceinline__ void glds16(const short* g, short* lds_base) {
    __builtin_amdgcn_global_load_lds(
        (const __attribute__((address_space(1))) void*)g,
        (__attribute__((address_space(3))) void*)lds_base, 16, 0, 0);
}

// ---------------------------------------------------------------------------
// masked time-instance-norm statistics: mean/rstd per (b,d)
// ---------------------------------------------------------------------------
__global__ __launch_bounds__(256) void tin_stats_k(
    const float* __restrict__ x, const int* __restrict__ lengths,
    float* __restrict__ mean, float* __restrict__ rstd)
{
    __shared__ float rs_[4][64];
    __shared__ float rq_[4][64];
    const int b = blockIdx.x >> 5;
    const int d0 = (blockIdx.x & 31) << 6;
    const int dl = threadIdx.x & 63;
    const int strip = threadIdx.x >> 6;
    const int len = lengths[b];
    const int d = d0 + dl;
    float s = 0.f, q = 0.f;
    for (int t = strip; t < len; t += 4) {
        float v = x[((size_t)(b*NT + t))*ND + d];
        s += v; q += v*v;
    }
    rs_[strip][dl] = s; rq_[strip][dl] = q;
    __syncthreads();
    if (threadIdx.x < 64) {
        float S = rs_[0][dl]+rs_[1][dl]+rs_[2][dl]+rs_[3][dl];
        float Q = rq_[0][dl]+rq_[1][dl]+rq_[2][dl]+rq_[3][dl];
        float inv = 1.f / (float)(len < 1 ? 1 : len);
        float mu = S * inv;
        float var = Q * inv - mu*mu;
        mean[b*ND + d] = mu;
        rstd[b*ND + d] = rsqrtf(var + 1e-5f);
    }
}

// ---------------------------------------------------------------------------
// instnorm(x) -> blocked-fragment bf16 hi/lo (A of proj GEMM)
// ---------------------------------------------------------------------------
#define SLN 264
__global__ __launch_bounds__(256) void tin_norm_k(
    const float* __restrict__ x, const int* __restrict__ lengths,
    const float* __restrict__ mean, const float* __restrict__ rstd,
    const float* __restrict__ g, const float* __restrict__ be,
    short* __restrict__ Oh, short* __restrict__ Ol)
{
    __shared__ float sT[16][SLN];
    const int tid = threadIdx.x;
    const int row = tid >> 4, c = tid & 15;
    const int m = blockIdx.x*16 + row;
    const int b = m >> 9, t = m & (NT-1);
    const int len = lengths[b];
    const int kg0 = blockIdx.y*256 + c*16;
    if (t >= len) {
#pragma unroll
        for (int i = 0; i < 16; ++i) sT[row][c*16 + i] = 0.f;
    } else {
#pragma unroll
        for (int qq = 0; qq < 4; ++qq) {
            const int kg = kg0 + qq*4;
            float4 v = *(const float4*)(x + (size_t)m*ND + kg);
            float4 mn = *(const float4*)(mean + b*ND + kg);
            float4 rr = *(const float4*)(rstd + b*ND + kg);
            float4 gg = *(const float4*)(g + kg);
            float4 bb = *(const float4*)(be + kg);
            sT[row][c*16+qq*4+0] = (v.x-mn.x)*rr.x*gg.x + bb.x;
            sT[row][c*16+qq*4+1] = (v.y-mn.y)*rr.y*gg.y + bb.y;
            sT[row][c*16+qq*4+2] = (v.z-mn.z)*rr.z*gg.z + bb.z;
            sT[row][c*16+qq*4+3] = (v.w-mn.w)*rr.w*gg.w + bb.w;
        }
    }
    __syncthreads();
#pragma unroll
    for (int q = 0; q < 2; ++q) {
        const int slot = tid + 256*q;
        const int tile = slot >> 6, ln2 = slot & 63;
        const int mr = ln2 & 15, kc = ln2 >> 4;
        float v[8];
        *(float4*)&v[0] = *(const float4*)&sT[mr][tile*32 + kc*8];
        *(float4*)&v[4] = *(const float4*)&sT[mr][tile*32 + kc*8 + 4];
        short8 h8, l8; cvt8(v, h8, l8);
        const size_t off = ((size_t)blockIdx.x*64 + blockIdx.y*8 + tile)*512 + ln2*8;
        *(short8*)(Oh + off) = h8;
        *(short8*)(Ol + off) = l8;
    }
}

// ---------------------------------------------------------------------------
// weight converter: W[N][K] fp32 row-major -> blocked hi/lo bf16
// ---------------------------------------------------------------------------
__global__ __launch_bounds__(256) void wconv_k(
    const float* __restrict__ W, short* __restrict__ Oh, short* __restrict__ Ol,
    int K, int nmod, int nvalid)
{
    __shared__ float sT[16][SLN];
    const int tid = threadIdx.x;
    const int row = tid >> 4, c = tid & 15;
    const int n = blockIdx.x*16 + row;
    const int rr = n % nmod;
    const int kg0 = blockIdx.y*256 + c*16;
    if (rr >= nvalid) {
#pragma unroll
        for (int i = 0; i < 16; ++i) sT[row][c*16 + i] = 0.f;
    } else {
        const int src = (n/nmod)*nvalid + rr;
#pragma unroll
        for (int qq = 0; qq < 4; ++qq) {
            float4 v = *(const float4*)(W + (size_t)src*K + kg0 + qq*4);
            *(float4*)&sT[row][c*16+qq*4] = v;
        }
    }
    __syncthreads();
#pragma unroll
    for (int q = 0; q < 2; ++q) {
        const int slot = tid + 256*q;
        const int tile = slot >> 6, ln2 = slot & 63;
        const int mr = ln2 & 15, kc = ln2 >> 4;
        float v[8];
        *(float4*)&v[0] = *(const float4*)&sT[mr][tile*32 + kc*8];
        *(float4*)&v[4] = *(const float4*)&sT[mr][tile*32 + kc*8 + 4];
        short8 h8, l8; cvt8(v, h8, l8);
        const size_t off = ((size_t)blockIdx.x*(K>>5) + blockIdx.y*8 + tile)*512 + ln2*8;
        *(short8*)(Oh + off) = h8;
        *(short8*)(Ol + off) = l8;
    }
}

// ---------------------------------------------------------------------------
// Split-bf16 MFMA GEMM, m97-style: direct global->LDS staging (width 16),
// optional split-K over gridDim.z with fp32 atomicAdd epilogue.
// EPI 0: C = acc (+bias, z==0 only when ATOMIC); 1: C += rs*acc; 2: tanh(acc+bias)
// ---------------------------------------------------------------------------
template<int MSUB, int NSUB, int EPI, int ATOMIC>
__global__ __launch_bounds__(256) void mgemm_k(
    const short* __restrict__ Ah, const short* __restrict__ Al,
    const short* __restrict__ Bh, const short* __restrict__ Bl,
    const float* __restrict__ bias, float* __restrict__ C,
    int ldc, int Nvalid, int K, const float* __restrict__ rsp)
{
    __shared__ __align__(16) short lds[(MSUB+NSUB)*1024];
    short* As_h = lds;
    short* As_l = lds + MSUB*512;
    short* Bs_h = lds + MSUB*1024;
    short* Bs_l = lds + MSUB*1024 + NSUB*512;
    const int tid = threadIdx.x, lane = tid & 63, w = tid >> 6;
    const int m0t = blockIdx.x * MSUB;
    const int n0t = blockIdx.y * NSUB;
    const int Ktiles = K >> 5;
    const int kslice = Ktiles / (int)gridDim.z;
    const int kt0 = blockIdx.z * kslice;
    constexpr int MI = MSUB/2, NI = NSUB/2;
    constexpr int ASG = MSUB/4, BSG = NSUB/4;
    const int wm = w >> 1, wn = w & 1;

    floatx4 acc[MI][NI] = {};

    for (int kk = 0; kk < kslice; ++kk) {
        const int kb = kt0 + kk;
        // ---- direct global->LDS staging; layout is lane-linear 16B ----
#pragma unroll
        for (int u = 0; u < ASG; ++u) {
            const int sub = w*ASG + u;
            const size_t off = ((size_t)(m0t + sub)*Ktiles + kb)*512 + lane*8;
            glds16(Ah + off, &As_h[sub*512]);
            glds16(Al + off, &As_l[sub*512]);
        }
#pragma unroll
        for (int u = 0; u < BSG; ++u) {
            const int sub = w*BSG + u;
            const size_t off = ((size_t)(n0t + sub)*Ktiles + kb)*512 + lane*8;
            glds16(Bh + off, &Bs_h[sub*512]);
            glds16(Bl + off, &Bs_l[sub*512]);
        }
        __syncthreads();   // drains vmcnt -> staged data visible
        // ---- fragments + MFMA ----
        short8 fah[MI], fal[MI], fbh[NI], fbl[NI];
#pragma unroll
        for (int i = 0; i < MI; ++i) {
            const int sub = wm*MI + i;
            fah[i] = *(const short8*)&As_h[sub*512 + lane*8];
            fal[i] = *(const short8*)&As_l[sub*512 + lane*8];
        }
#pragma unroll
        for (int j = 0; j < NI; ++j) {
            const int sub = wn*NI + j;
            fbh[j] = *(const short8*)&Bs_h[sub*512 + lane*8];
            fbl[j] = *(const short8*)&Bs_l[sub*512 + lane*8];
        }
#pragma unroll
        for (int i = 0; i < MI; ++i)
#pragma unroll
            for (int j = 0; j < NI; ++j) {
                acc[i][j] = __builtin_amdgcn_mfma_f32_16x16x32_bf16(fah[i], fbh[j], acc[i][j], 0, 0, 0);
                acc[i][j] = __builtin_amdgcn_mfma_f32_16x16x32_bf16(fah[i], fbl[j], acc[i][j], 0, 0, 0);
                acc[i][j] = __builtin_amdgcn_mfma_f32_16x16x32_bf16(fal[i], fbh[j], acc[i][j], 0, 0, 0);
            }
        __syncthreads();   // all waves done reading before next overwrite
    }

    const float rs = (EPI == 1) ? rsp[0] : 0.f;
    const int lc = lane >> 4, col = lane & 15;
    const bool addb = (EPI != 1) && bias && (!ATOMIC || blockIdx.z == 0);
#pragma unroll
    for (int j = 0; j < NI; ++j) {
        const int n = (n0t + wn*NI + j)*16 + col;
        if (n < Nvalid) {
            const float bv = addb ? bias[n] : 0.f;
#pragma unroll
            for (int i = 0; i < MI; ++i) {
                const int mb = (m0t + wm*MI + i)*16 + lc*4;
#pragma unroll
                for (int r = 0; r < 4; ++r) {
                    float v = acc[i][j][r];
                    float* cp = C + (size_t)(mb + r)*ldc + n;
                    if (ATOMIC) {
                        if (EPI == 1) atomicAdd(cp, rs*v);
                        else          atomicAdd(cp, v + bv);
                    } else {
                        if (EPI == 0)      *cp = v + bv;
                        else if (EPI == 1) *cp = fmaf(rs, v, *cp);
                        else               *cp = tanhf(v + bv);
                    }
                }
            }
        }
    }
}

// ---------------------------------------------------------------------------
// LayerNorm over DM=256 -> blocked bf16 hi/lo (+ optional fp32 row-major)
// ---------------------------------------------------------------------------
template<int WF32>
__global__ __launch_bounds__(256) void ln_blk_k(
    const float* __restrict__ in, const float* __restrict__ g,
    const float* __restrict__ b,
    short* __restrict__ Oh, short* __restrict__ Ol, float* __restrict__ o32)
{
    __shared__ float sT[16][SLN];
    const int tid = threadIdx.x;
    const int row = tid >> 4, c = tid & 15;
    const int m = blockIdx.x*16 + row;
    float v[16];
#pragma unroll
    for (int qq = 0; qq < 4; ++qq)
        *(float4*)&v[qq*4] = *(const float4*)(in + (size_t)m*NDM + c*16 + qq*4);
    float s = 0.f, q = 0.f;
#pragma unroll
    for (int i = 0; i < 16; ++i) { s += v[i]; q += v[i]*v[i]; }
#pragma unroll
    for (int o = 8; o; o >>= 1) { s += __shfl_xor(s, o); q += __shfl_xor(q, o); }
    const float mu = s * (1.f/NDM);
    const float r = rsqrtf(q*(1.f/NDM) - mu*mu + 1e-5f);
#pragma unroll
    for (int i = 0; i < 16; ++i) {
        const int kg = c*16 + i;
        v[i] = (v[i]-mu)*r*g[kg] + b[kg];
        sT[row][kg] = v[i];
    }
    if (WF32) {
#pragma unroll
        for (int qq = 0; qq < 4; ++qq)
            *(float4*)(o32 + (size_t)m*NDM + c*16 + qq*4) = *(const float4*)&v[qq*4];
    }
    __syncthreads();
#pragma unroll
    for (int qv = 0; qv < 2; ++qv) {
        const int slot = tid + 256*qv;
        const int tile = slot >> 6, ln2 = slot & 63;
        const int mr = ln2 & 15, kc = ln2 >> 4;
        float vv[8];
        *(float4*)&vv[0] = *(const float4*)&sT[mr][tile*32 + kc*8];
        *(float4*)&vv[4] = *(const float4*)&sT[mr][tile*32 + kc*8 + 4];
        short8 h8, l8; cvt8(vv, h8, l8);
        const size_t off = ((size_t)blockIdx.x*8 + tile)*512 + ln2*8;
        *(short8*)(Oh + off) = h8;
        *(short8*)(Ol + off) = l8;
    }
}

// ---------------------------------------------------------------------------
// depthwise causal conv(4) + silu -> xc fp32 row-major AND blocked hi/lo
// ---------------------------------------------------------------------------
#define SCV 520
__global__ __launch_bounds__(256) void conv_blk_k(
    const float* __restrict__ xz, const float* __restrict__ cw,
    const float* __restrict__ cb, float* __restrict__ xc32,
    short* __restrict__ Oh, short* __restrict__ Ol)
{
    __shared__ float sT[16][SCV];
    const int tid = threadIdx.x;
    const int row = tid >> 4, cg = tid & 15;
    const int m = blockIdx.x*16 + row;
    const int t = m & (NT-1);
#pragma unroll
    for (int grp = 0; grp < 4; ++grp) {
        const int ch = cg*32 + grp*8;
        float a[8];
        *(float4*)&a[0] = *(const float4*)(cb + ch);
        *(float4*)&a[4] = *(const float4*)(cb + ch + 4);
        float4 wv[8];
#pragma unroll
        for (int i = 0; i < 8; ++i) wv[i] = *(const float4*)(cw + (ch+i)*4);
#pragma unroll
        for (int kk = 0; kk < 4; ++kk) {
            if (t - 3 + kk >= 0) {
                const float* xp = xz + (size_t)(m-3+kk)*(2*NDI) + ch;
                float xv[8];
                *(float4*)&xv[0] = *(const float4*)xp;
                *(float4*)&xv[4] = *(const float4*)(xp + 4);
                const float tap[8] = {
                    kk==0?wv[0].x:kk==1?wv[0].y:kk==2?wv[0].z:wv[0].w,
                    kk==0?wv[1].x:kk==1?wv[1].y:kk==2?wv[1].z:wv[1].w,
                    kk==0?wv[2].x:kk==1?wv[2].y:kk==2?wv[2].z:wv[2].w,
                    kk==0?wv[3].x:kk==1?wv[3].y:kk==2?wv[3].z:wv[3].w,
                    kk==0?wv[4].x:kk==1?wv[4].y:kk==2?wv[4].z:wv[4].w,
                    kk==0?wv[5].x:kk==1?wv[5].y:kk==2?wv[5].z:wv[5].w,
                    kk==0?wv[6].x:kk==1?wv[6].y:kk==2?wv[6].z:wv[6].w,
                    kk==0?wv[7].x:kk==1?wv[7].y:kk==2?wv[7].z:wv[7].w};
#pragma unroll
                for (int i = 0; i < 8; ++i) a[i] = fmaf(xv[i], tap[i], a[i]);
            }
        }
#pragma unroll
        for (int i = 0; i < 8; ++i) a[i] = a[i] / (1.f + __expf(-a[i]));
        *(float4*)&sT[row][ch] = *(const float4*)&a[0];
        *(float4*)&sT[row][ch+4] = *(const float4*)&a[4];
        *(float4*)(xc32 + (size_t)m*NDI + ch) = *(const float4*)&a[0];
        *(float4*)(xc32 + (size_t)m*NDI + ch + 4) = *(const float4*)&a[4];
    }
    __syncthreads();
#pragma unroll
    for (int q = 0; q < 4; ++q) {
        const int slot = tid + 256*q;
        const int tile = slot >> 6, ln2 = slot & 63;
        const int mr = ln2 & 15, kc = ln2 >> 4;
        float vv[8];
        *(float4*)&vv[0] = *(const float4*)&sT[mr][tile*32 + kc*8];
        *(float4*)&vv[4] = *(const float4*)&sT[mr][tile*32 + kc*8 + 4];
        short8 h8, l8; cvt8(vv, h8, l8);
        const size_t off = ((size_t)blockIdx.x*16 + tile)*512 + ln2*8;
        *(short8*)(Oh + off) = h8;
        *(short8*)(Ol + off) = l8;
    }
}

// ---------------------------------------------------------------------------
// dt[m][d] = softplus(dbc[m][0:16] . dtw[d] + dtb[d]); grid NM blocks
// ---------------------------------------------------------------------------
__global__ __launch_bounds__(256) void dt_k(
    const float* __restrict__ dbc, const float* __restrict__ dtw,
    const float* __restrict__ dtb, float* __restrict__ dt)
{
    const int m = blockIdx.x;
    const float* rsrc = dbc + (size_t)m*48;
    float rv[16];
#pragma unroll
    for (int i = 0; i < 16; ++i) rv[i] = rsrc[i];
#pragma unroll
    for (int hh = 0; hh < 2; ++hh) {
        const int d = hh*256 + threadIdx.x;
        const float* wr = dtw + d*16;
        float a = dtb[d];
#pragma unroll
        for (int i = 0; i < 16; ++i) a = fmaf(rv[i], wr[i], a);
        dt[(size_t)m*NDI + d] = (a > 20.f) ? a : log1pf(__expf(a));
    }
}

// ---------------------------------------------------------------------------
// selective scan: 4 states/thread, DPP quad reduction, LDS-transposed dt/x,
// register double-buffered 4-step groups. block=256 (64 ch), grid NB*8.
// ---------------------------------------------------------------------------
__global__ __launch_bounds__(256) void scan_k(
    const float* __restrict__ dbc, const float* __restrict__ dtp,
    const float* __restrict__ xcp, const float* __restrict__ xz,
    const float* __restrict__ Alog, const float* __restrict__ Dp,
    short* __restrict__ Yh, short* __restrict__ Yl)
{
    __shared__ float sBC[64][32];
    __shared__ float sDt[64][68];
    __shared__ float sX[64][68];
    __shared__ float sY[64][68];
    const int tid = threadIdx.x;
    const int w = tid >> 6, lane = tid & 63;
    const int dl = lane >> 2, sg = lane & 3;
    const int b = blockIdx.x >> 3;
    const int d0 = (blockIdx.x & 7) << 6;
    const int dloc = w*16 + dl;
    const int d = d0 + dloc;
    float ar[4];
    {
        float4 al4 = *(const float4*)(Alog + d*NDS + sg*4);
        ar[0] = -__expf(al4.x); ar[1] = -__expf(al4.y);
        ar[2] = -__expf(al4.z); ar[3] = -__expf(al4.w);
    }
    const float Dpv = Dp[d];
    float hr[4] = {0.f, 0.f, 0.f, 0.f};
    const int mbase = b*NT;
    const int srow = tid >> 2, sq = (tid & 3) << 3;
    const int tr = tid >> 2, qq = tid & 3;

    for (int c0 = 0; c0 < NT; c0 += 64) {
        __syncthreads();
        {
            const float* dp_ = dbc + (size_t)(mbase + c0 + srow)*48 + 16 + sq;
            *(float4*)&sBC[srow][sq]   = *(const float4*)dp_;
            *(float4*)&sBC[srow][sq+4] = *(const float4*)(dp_ + 4);
        }
        {
            const float* dsrc = dtp + (size_t)(mbase + c0 + tr)*NDI + d0 + qq*16;
            const float* xsrc = xcp + (size_t)(mbase + c0 + tr)*NDI + d0 + qq*16;
#pragma unroll
            for (int i = 0; i < 4; ++i) {
                float4 dv = *(const float4*)(dsrc + i*4);
                float4 xv = *(const float4*)(xsrc + i*4);
                const int dd = qq*16 + i*4;
                sDt[dd+0][tr]=dv.x; sDt[dd+1][tr]=dv.y; sDt[dd+2][tr]=dv.z; sDt[dd+3][tr]=dv.w;
                sX[dd+0][tr]=xv.x;  sX[dd+1][tr]=xv.y;  sX[dd+2][tr]=xv.z;  sX[dd+3][tr]=xv.w;
            }
        }
        __syncthreads();
        float4 Bt[2][4], Ct[2][4], dt4[2], x4[2];
#pragma unroll
        for (int i = 0; i < 4; ++i) {
            Bt[0][i] = *(const float4*)&sBC[i][sg*4];
            Ct[0][i] = *(const float4*)&sBC[i][16 + sg*4];
        }
        dt4[0] = *(const float4*)&sDt[dloc][0];
        x4[0]  = *(const float4*)&sX[dloc][0];
#pragma unroll
        for (int g = 0; g < 16; ++g) {
            const int cur = g & 1, nxt = cur ^ 1;
            if (g < 15) {
                const int t4 = (g+1)*4;
#pragma unroll
                for (int i = 0; i < 4; ++i) {
                    Bt[nxt][i] = *(const float4*)&sBC[t4+i][sg*4];
                    Ct[nxt][i] = *(const float4*)&sBC[t4+i][16 + sg*4];
                }
                dt4[nxt] = *(const float4*)&sDt[dloc][t4];
                x4[nxt]  = *(const float4*)&sX[dloc][t4];
            }
#pragma unroll
            for (int i = 0; i < 4; ++i) {
                const float dtv = (i==0)?dt4[cur].x:(i==1)?dt4[cur].y:(i==2)?dt4[cur].z:dt4[cur].w;
                const float xv  = (i==0)?x4[cur].x:(i==1)?x4[cur].y:(i==2)?x4[cur].z:x4[cur].w;
                const float4 Bv = Bt[cur][i];
                const float4 Cv = Ct[cur][i];
                const float dbx = dtv * xv;
                float pa0 = __expf(dtv*ar[0]);
                float pa1 = __expf(dtv*ar[1]);
                float pa2 = __expf(dtv*ar[2]);
                float pa3 = __expf(dtv*ar[3]);
                hr[0] = fmaf(pa0, hr[0], dbx*Bv.x);
                hr[1] = fmaf(pa1, hr[1], dbx*Bv.y);
                hr[2] = fmaf(pa2, hr[2], dbx*Bv.z);
                hr[3] = fmaf(pa3, hr[3], dbx*Bv.w);
                float cp = hr[0]*Cv.x;
                cp = fmaf(hr[1], Cv.y, cp);
                cp = fmaf(hr[2], Cv.z, cp);
                cp = fmaf(hr[3], Cv.w, cp);
                cp = quad_sum(cp);
                if (sg == 0) sY[g*4 + i][dloc] = fmaf(Dpv, xv, cp);
            }
        }
        __syncthreads();
#pragma unroll
        for (int q = 0; q < 2; ++q) {
            const int slot = tid + 256*q;
            const int tile = slot >> 6, ln2 = slot & 63;
            const int tm = tile >> 1, tk = tile & 1;
            const int mr = ln2 & 15, kc = ln2 >> 4;
            const int m = mbase + c0 + tm*16 + mr;
            const int kd = d0 + tk*32 + kc*8;
            float yv[8];
            *(float4*)&yv[0] = *(const float4*)&sY[tm*16 + mr][tk*32 + kc*8];
            *(float4*)&yv[4] = *(const float4*)&sY[tm*16 + mr][tk*32 + kc*8 + 4];
            float zv[8];
            *(float4*)&zv[0] = *(const float4*)(xz + (size_t)m*(2*NDI) + NDI + kd);
            *(float4*)&zv[4] = *(const float4*)(xz + (size_t)m*(2*NDI) + NDI + kd + 4);
#pragma unroll
            for (int i = 0; i < 8; ++i)
                yv[i] *= zv[i] / (1.f + __expf(-zv[i]));
            short8 h8, l8; cvt8(yv, h8, l8);
            const size_t off = ((size_t)(m>>4)*16 + (kd>>5))*512 + ln2*8;
            *(short8*)(Yh + off) = h8;
            *(short8*)(Yl + off) = l8;
        }
    }
}

// ---------------------------------------------------------------------------
__global__ __launch_bounds__(64) void score_k(
    const float* __restrict__ t1, const float* __restrict__ w2,
    float* __restrict__ sout)
{
    const int m = blockIdx.x;
    const int lane = threadIdx.x;
    float v = t1[(size_t)m*NH + lane]*w2[lane]
            + t1[(size_t)m*NH + 64 + lane]*w2[64 + lane];
#pragma unroll
    for (int o = 32; o; o >>= 1) v += __shfl_xor(v, o);
    if (lane == 0) sout[m] = v;
}

__global__ __launch_bounds__(256) void pool_k(
    const float* __restrict__ sbuf, const float* __restrict__ u,
    const int* __restrict__ lengths, float* __restrict__ ctx)
{
    __shared__ float al[NT];
    __shared__ float red[256];
    const int b = blockIdx.x;
    const int tid = threadIdx.x;
    const int len = lengths[b];
    float mx = -3.4e38f;
    for (int t = tid; t < len; t += 256) mx = fmaxf(mx, sbuf[b*NT + t]);
    red[tid] = mx; __syncthreads();
    for (int o = 128; o; o >>= 1) { if (tid < o) red[tid] = fmaxf(red[tid], red[tid+o]); __syncthreads(); }
    mx = red[0];
    __syncthreads();
    float sm = 0.f;
    for (int t = tid; t < len; t += 256) {
        float e = __expf(sbuf[b*NT + t] - mx);
        al[t] = e; sm += e;
    }
    red[tid] = sm; __syncthreads();
    for (int o = 128; o; o >>= 1) { if (tid < o) red[tid] += red[tid+o]; __syncthreads(); }
    const float rZ = 1.f / red[0];
    float acc = 0.f;
    const float* up = u + (size_t)b*NT*NDM + tid;
    for (int t = 0; t < len; ++t) acc = fmaf(al[t], up[(size_t)t*NDM], acc);
    ctx[b*NDM + tid] = acc * rZ;
}

__global__ __launch_bounds__(64) void head_k(
    const float* __restrict__ ctx, const float* __restrict__ hw,
    const float* __restrict__ hb, float* __restrict__ o)
{
    const int b = blockIdx.x;
    const int lane = threadIdx.x;
    const float4 c4 = *(const float4*)(ctx + b*NDM + lane*4);
#pragma unroll
    for (int c = 0; c < NNC; ++c) {
        const float4 w4 = *(const float4*)(hw + c*NDM + lane*4);
        float v = c4.x*w4.x + c4.y*w4.y + c4.z*w4.z + c4.w*w4.w;
#pragma unroll
        for (int off = 32; off; off >>= 1) v += __shfl_xor(v, off);
        if (lane == 0) o[b*NNC + c] = v + hb[c];
    }
}

// ---------------------------------------------------------------------------
extern "C" void kernel_launch(void* const* d_in, const int* in_sizes, int n_in,
                              void* d_out, int out_size, void* d_ws, size_t ws_size,
                              hipStream_t stream)
{
    (void)in_sizes; (void)n_in; (void)out_size; (void)ws_size;
    const float* x         = (const float*)d_in[0];
    const int*   lengths   = (const int*)  d_in[1];
    const float* tin_gamma = (const float*)d_in[2];
    const float* tin_beta  = (const float*)d_in[3];
    const float* proj_w    = (const float*)d_in[4];
    const float* proj_b    = (const float*)d_in[5];
    const float* ln_g      = (const float*)d_in[6];
    const float* ln_b      = (const float*)d_in[7];
    const float* in_proj_w = (const float*)d_in[8];
    const float* conv_w    = (const float*)d_in[9];
    const float* conv_b    = (const float*)d_in[10];
    const float* x_proj_w  = (const float*)d_in[11];
    const float* dt_proj_w = (const float*)d_in[12];
    const float* dt_proj_b = (const float*)d_in[13];
    const float* A_log     = (const float*)d_in[14];
    const float* D_param   = (const float*)d_in[15];
    const float* out_proj_w= (const float*)d_in[16];
    const float* out_ln_g  = (const float*)d_in[17];
    const float* out_ln_b  = (const float*)d_in[18];
    const float* res_scale = (const float*)d_in[19];
    const float* attn_w1   = (const float*)d_in[20];
    const float* attn_b1   = (const float*)d_in[21];
    const float* attn_w2   = (const float*)d_in[22];
    const float* head_w    = (const float*)d_in[23];
    const float* head_b    = (const float*)d_in[24];
    float* out = (float*)d_out;

    float* ws = (float*)d_ws;
    float* mean   = ws;                         // 65536
    float* rstd   = mean + 65536;               // 65536
    float* hbuf   = rstd + 65536;               // NM*NDM
    float* ubuf32 = hbuf + (size_t)NM*NDM;      // NM*NDM
    float* dbc    = ubuf32 + (size_t)NM*NDM;    // NM*48
    float* t1     = dbc + (size_t)NM*48;        // NM*NH
    float* sbuf   = t1 + (size_t)NM*NH;         // NM
    float* ctx    = sbuf + NM;                  // NB*NDM
    float* fend   = ctx + NB*NDM;
    short* ublk_h = (short*)fend;
    short* ublk_l = ublk_h + (size_t)NM*NDM;
    short* xcb_h  = ublk_l + (size_t)NM*NDM;
    short* xcb_l  = xcb_h + (size_t)NM*NDI;
    short* yq_h   = xcb_l + (size_t)NM*NDI;
    short* yq_l   = yq_h + (size_t)NM*NDI;
    short* pw_h   = yq_l + (size_t)NM*NDI;
    short* pw_l   = pw_h + (size_t)256*2048;
    short* iw_h   = pw_l + (size_t)256*2048;
    short* iw_l   = iw_h + (size_t)4*1024*256;
    short* xw_h   = iw_l + (size_t)4*1024*256;
    short* xw_l   = xw_h + (size_t)4*64*512;
    short* ow_h   = xw_l + (size_t)4*64*512;
    short* ow_l   = ow_h + (size_t)4*256*512;
    short* aw_h   = ow_l + (size_t)4*256*512;
    short* aw_l   = aw_h + (size_t)128*256;
    float* over   = (float*)(aw_l + (size_t)128*256);
    short* xn_h   = (short*)over;
    short* xn_l   = xn_h + (size_t)NM*ND;
    float* xz     = over;
    float* xc32   = over + (size_t)NM*2*NDI;
    float* dtb_   = xc32 + (size_t)NM*NDI;

    const dim3 blk(256);

    wconv_k<<<dim3(16, 8), blk, 0, stream>>>(proj_w, pw_h, pw_l, 2048, 1<<28, 1<<28);
    wconv_k<<<dim3(256, 1), blk, 0, stream>>>(in_proj_w, iw_h, iw_l, 256, 1<<28, 1<<28);
    wconv_k<<<dim3(16, 2), blk, 0, stream>>>(x_proj_w, xw_h, xw_l, 512, 64, 48);
    wconv_k<<<dim3(64, 2), blk, 0, stream>>>(out_proj_w, ow_h, ow_l, 512, 1<<28, 1<<28);
    wconv_k<<<dim3(8, 1), blk, 0, stream>>>(attn_w1, aw_h, aw_l, 256, 1<<28, 1<<28);

    tin_stats_k<<<dim3(NB*32), blk, 0, stream>>>(x, lengths, mean, rstd);
    tin_norm_k<<<dim3(NM/16, 8), blk, 0, stream>>>(x, lengths, mean, rstd,
        tin_gamma, tin_beta, xn_h, xn_l);
    // proj: split-K=4, atomic accumulate into zeroed hbuf (z0 adds bias)
    hipMemsetAsync(hbuf, 0, (size_t)NM*NDM*sizeof(float), stream);
    mgemm_k<4,8,0,1><<<dim3(256, 2, 4), blk, 0, stream>>>(
        xn_h, xn_l, pw_h, pw_l, proj_b, hbuf, NDM, NDM, 2048, nullptr);

    for (int l = 0; l < NL; ++l) {
        ln_blk_k<0><<<dim3(NM/16), blk, 0, stream>>>(
            hbuf, ln_g + l*NDM, ln_b + l*NDM, ublk_h, ublk_l, nullptr);
        mgemm_k<8,8,0,0><<<dim3(128, 8, 1), blk, 0, stream>>>(
            ublk_h, ublk_l, iw_h + (size_t)l*1024*256, iw_l + (size_t)l*1024*256,
            nullptr, xz, 2*NDI, 2*NDI, NDM, nullptr);
        conv_blk_k<<<dim3(NM/16), blk, 0, stream>>>(
            xz, conv_w + (size_t)l*NDI*4, conv_b + (size_t)l*NDI, xc32, xcb_h, xcb_l);
        // x_proj: split-K=2, atomic into zeroed dbc
        hipMemsetAsync(dbc, 0, (size_t)NM*48*sizeof(float), stream);
        mgemm_k<4,4,0,1><<<dim3(256, 1, 2), blk, 0, stream>>>(
            xcb_h, xcb_l, xw_h + (size_t)l*64*512, xw_l + (size_t)l*64*512,
            nullptr, dbc, 48, 48, 512, nullptr);
        dt_k<<<dim3(NM), blk, 0, stream>>>(
            dbc, dt_proj_w + (size_t)l*NDI*NR, dt_proj_b + (size_t)l*NDI, dtb_);
        scan_k<<<dim3(NB*8), blk, 0, stream>>>(
            dbc, dtb_, xc32, xz, A_log + (size_t)l*NDI*NDS, D_param + (size_t)l*NDI,
            yq_h, yq_l);
        // out_proj: split-K=2, atomic h += rs*partial (no init needed)
        mgemm_k<4,8,1,1><<<dim3(256, 2, 2), blk, 0, stream>>>(
            yq_h, yq_l, ow_h + (size_t)l*256*512, ow_l + (size_t)l*256*512,
            nullptr, hbuf, NDM, NDM, 512, res_scale);
    }

    ln_blk_k<1><<<dim3(NM/16), blk, 0, stream>>>(
        hbuf, out_ln_g, out_ln_b, ublk_h, ublk_l, ubuf32);
    mgemm_k<4,4,2,0><<<dim3(256, 2, 1), blk, 0, stream>>>(
        ublk_h, ublk_l, aw_h, aw_l, attn_b1, t1, NH, NH, 256, nullptr);
    score_k<<<dim3(NM), dim3(64), 0, stream>>>(t1, attn_w2, sbuf);
    pool_k<<<dim3(NB), blk, 0, stream>>>(sbuf, ubuf32, lengths, ctx);
    head_k<<<dim3(NB), dim3(64), 0, stream>>>(ctx, head_w, head_b, out);
}

// Round 6
// 1503.693 us; speedup vs baseline: 1.0534x; 1.0534x over previous
//
#include <hip/hip_runtime.h>

#define NB 32       // B
#define NT 512      // T
#define ND 2048     // D
#define NDM 256     // DM
#define NDI 512     // DI
#define NDS 16      // DS
#define NR 16       // R
#define NH 128      // H
#define NNC 8       // NC
#define NL 4        // L
#define NM (NB*NT)  // 16384 tokens

typedef __attribute__((ext_vector_type(8))) short short8;
typedef __attribute__((ext_vector_type(4))) float floatx4;

__device__ __forceinline__ unsigned short f2bf_rn(float f) {
    unsigned u = __builtin_bit_cast(unsigned, f);
    u += 0x7FFFu + ((u >> 16) & 1u);
    return (unsigned short)(u >> 16);
}
__device__ __forceinline__ void cvt8(const float* v, short8& h8, short8& l8) {
#pragma unroll
    for (int q = 0; q < 8; ++q) {
        unsigned short hb = f2bf_rn(v[q]);
        float hf = __builtin_bit_cast(float, (unsigned)hb << 16);
        h8[q] = (short)hb;
        l8[q] = (short)f2bf_rn(v[q] - hf);
    }
}
// sum over the 4 lanes of a quad via DPP (VALU pipe, no LDS)
__device__ __forceinline__ float quad_sum(float v) {
    int i = __builtin_bit_cast(int, v);
    int j = __builtin_amdgcn_update_dpp(0, i, 0xB1, 0xF, 0xF, true); // quad xor1
    v += __builtin_bit_cast(float, j);
    i = __builtin_bit_cast(int, v);
    j = __builtin_amdgcn_update_dpp(0, i, 0x4E, 0xF, 0xF, true);     // quad xor2
    v += __builtin_bit_cast(float, j);
    return v;
}
// async global->LDS, 16B per lane; lds base must be wave-uniform (HW adds lane*16)
__device__ __forceinline__ void glds16(const short* g, short* lds_base) {
    __builtin_amdgcn_global_load_lds(
        (const __attribute__((address_space(1))) void*)g,
        (__attribute__((address_space(3))) void*)lds_base, 16, 0, 0);
}

// ---------------------------------------------------------------------------
// masked time-instance-norm statistics: mean/rstd per (b,d)
// ---------------------------------------------------------------------------
__global__ __launch_bounds__(256) void tin_stats_k(
    const float* __restrict__ x, const int* __restrict__ lengths,
    float* __restrict__ mean, float* __restrict__ rstd)
{
    __shared__ float rs_[4][64];
    __shared__ float rq_[4][64];
    const int b = blockIdx.x >> 5;
    const int d0 = (blockIdx.x & 31) << 6;
    const int dl = threadIdx.x & 63;
    const int strip = threadIdx.x >> 6;
    const int len = lengths[b];
    const int d = d0 + dl;
    float s = 0.f, q = 0.f;
    for (int t = strip; t < len; t += 4) {
        float v = x[((size_t)(b*NT + t))*ND + d];
        s += v; q += v*v;
    }
    rs_[strip][dl] = s; rq_[strip][dl] = q;
    __syncthreads();
    if (threadIdx.x < 64) {
        float S = rs_[0][dl]+rs_[1][dl]+rs_[2][dl]+rs_[3][dl];
        float Q = rq_[0][dl]+rq_[1][dl]+rq_[2][dl]+rq_[3][dl];
        float inv = 1.f / (float)(len < 1 ? 1 : len);
        float mu = S * inv;
        float var = Q * inv - mu*mu;
        mean[b*ND + d] = mu;
        rstd[b*ND + d] = rsqrtf(var + 1e-5f);
    }
}

// ---------------------------------------------------------------------------
// instnorm(x) -> blocked-fragment bf16 hi/lo (A of proj GEMM)
// ---------------------------------------------------------------------------
#define SLN 264
__global__ __launch_bounds__(256) void tin_norm_k(
    const float* __restrict__ x, const int* __restrict__ lengths,
    const float* __restrict__ mean, const float* __restrict__ rstd,
    const float* __restrict__ g, const float* __restrict__ be,
    short* __restrict__ Oh, short* __restrict__ Ol)
{
    __shared__ float sT[16][SLN];
    const int tid = threadIdx.x;
    const int row = tid >> 4, c = tid & 15;
    const int m = blockIdx.x*16 + row;
    const int b = m >> 9, t = m & (NT-1);
    const int len = lengths[b];
    const int kg0 = blockIdx.y*256 + c*16;
    if (t >= len) {
#pragma unroll
        for (int i = 0; i < 16; ++i) sT[row][c*16 + i] = 0.f;
    } else {
#pragma unroll
        for (int qq = 0; qq < 4; ++qq) {
            const int kg = kg0 + qq*4;
            float4 v = *(const float4*)(x + (size_t)m*ND + kg);
            float4 mn = *(const float4*)(mean + b*ND + kg);
            float4 rr = *(const float4*)(rstd + b*ND + kg);
            float4 gg = *(const float4*)(g + kg);
            float4 bb = *(const float4*)(be + kg);
            sT[row][c*16+qq*4+0] = (v.x-mn.x)*rr.x*gg.x + bb.x;
            sT[row][c*16+qq*4+1] = (v.y-mn.y)*rr.y*gg.y + bb.y;
            sT[row][c*16+qq*4+2] = (v.z-mn.z)*rr.z*gg.z + bb.z;
            sT[row][c*16+qq*4+3] = (v.w-mn.w)*rr.w*gg.w + bb.w;
        }
    }
    __syncthreads();
#pragma unroll
    for (int q = 0; q < 2; ++q) {
        const int slot = tid + 256*q;
        const int tile = slot >> 6, ln2 = slot & 63;
        const int mr = ln2 & 15, kc = ln2 >> 4;
        float v[8];
        *(float4*)&v[0] = *(const float4*)&sT[mr][tile*32 + kc*8];
        *(float4*)&v[4] = *(const float4*)&sT[mr][tile*32 + kc*8 + 4];
        short8 h8, l8; cvt8(v, h8, l8);
        const size_t off = ((size_t)blockIdx.x*64 + blockIdx.y*8 + tile)*512 + ln2*8;
        *(short8*)(Oh + off) = h8;
        *(short8*)(Ol + off) = l8;
    }
}

// ---------------------------------------------------------------------------
// weight converter: W[N][K] fp32 row-major -> blocked hi/lo bf16
// ---------------------------------------------------------------------------
__global__ __launch_bounds__(256) void wconv_k(
    const float* __restrict__ W, short* __restrict__ Oh, short* __restrict__ Ol,
    int K, int nmod, int nvalid)
{
    __shared__ float sT[16][SLN];
    const int tid = threadIdx.x;
    const int row = tid >> 4, c = tid & 15;
    const int n = blockIdx.x*16 + row;
    const int rr = n % nmod;
    const int kg0 = blockIdx.y*256 + c*16;
    if (rr >= nvalid) {
#pragma unroll
        for (int i = 0; i < 16; ++i) sT[row][c*16 + i] = 0.f;
    } else {
        const int src = (n/nmod)*nvalid + rr;
#pragma unroll
        for (int qq = 0; qq < 4; ++qq) {
            float4 v = *(const float4*)(W + (size_t)src*K + kg0 + qq*4);
            *(float4*)&sT[row][c*16+qq*4] = v;
        }
    }
    __syncthreads();
#pragma unroll
    for (int q = 0; q < 2; ++q) {
        const int slot = tid + 256*q;
        const int tile = slot >> 6, ln2 = slot & 63;
        const int mr = ln2 & 15, kc = ln2 >> 4;
        float v[8];
        *(float4*)&v[0] = *(const float4*)&sT[mr][tile*32 + kc*8];
        *(float4*)&v[4] = *(const float4*)&sT[mr][tile*32 + kc*8 + 4];
        short8 h8, l8; cvt8(v, h8, l8);
        const size_t off = ((size_t)blockIdx.x*(K>>5) + blockIdx.y*8 + tile)*512 + ln2*8;
        *(short8*)(Oh + off) = h8;
        *(short8*)(Ol + off) = l8;
    }
}

// ---------------------------------------------------------------------------
// Split-bf16 MFMA GEMM: glds direct staging + double-buffered LDS,
// ONE barrier per K-tile (barrier's vmcnt drain waits on glds issued a full
// compute phase earlier -> latency hidden). No atomics, no split-K.
// EPI 0: C = acc (+bias); 1: C += rs*acc; 2: C = tanh(acc+bias)
// ---------------------------------------------------------------------------
template<int MSUB, int NSUB, int EPI>
__global__ __launch_bounds__(256) void mgemm_k(
    const short* __restrict__ Ah, const short* __restrict__ Al,
    const short* __restrict__ Bh, const short* __restrict__ Bl,
    const float* __restrict__ bias, float* __restrict__ C,
    int ldc, int Nvalid, int K, const float* __restrict__ rsp)
{
    constexpr int STG = (MSUB+NSUB)*1024;   // shorts per buffer
    __shared__ __align__(16) short lds[2*STG];
    const int tid = threadIdx.x, lane = tid & 63, w = tid >> 6;
    const int m0t = blockIdx.x * MSUB;
    const int n0t = blockIdx.y * NSUB;
    const int Ktiles = K >> 5;
    constexpr int MI = MSUB/2, NI = NSUB/2;
    constexpr int ASG = MSUB/4, BSG = NSUB/4;
    const int wm = w >> 1, wn = w & 1;

    floatx4 acc[MI][NI] = {};

    // stage k-tile kb into buffer buf (async glds, wave-uniform LDS bases)
    auto stage = [&](int kb, int buf) {
        short* As_h = lds + buf*STG;
        short* As_l = As_h + MSUB*512;
        short* Bs_h = lds + buf*STG + MSUB*1024;
        short* Bs_l = Bs_h + NSUB*512;
#pragma unroll
        for (int u = 0; u < ASG; ++u) {
            const int sub = w*ASG + u;
            const size_t off = ((size_t)(m0t + sub)*Ktiles + kb)*512 + lane*8;
            glds16(Ah + off, &As_h[sub*512]);
            glds16(Al + off, &As_l[sub*512]);
        }
#pragma unroll
        for (int u = 0; u < BSG; ++u) {
            const int sub = w*BSG + u;
            const size_t off = ((size_t)(n0t + sub)*Ktiles + kb)*512 + lane*8;
            glds16(Bh + off, &Bs_h[sub*512]);
            glds16(Bl + off, &Bs_l[sub*512]);
        }
    };

    stage(0, 0);
    for (int kb = 0; kb < Ktiles; ++kb) {
        __syncthreads();            // drains vmcnt: buf cur is now valid
        if (kb + 1 < Ktiles) stage(kb + 1, (kb + 1) & 1);   // async prefetch
        const int buf = kb & 1;
        const short* As_h = lds + buf*STG;
        const short* As_l = As_h + MSUB*512;
        const short* Bs_h = lds + buf*STG + MSUB*1024;
        const short* Bs_l = Bs_h + NSUB*512;
        short8 fah[MI], fal[MI], fbh[NI], fbl[NI];
#pragma unroll
        for (int i = 0; i < MI; ++i) {
            const int sub = wm*MI + i;
            fah[i] = *(const short8*)&As_h[sub*512 + lane*8];
            fal[i] = *(const short8*)&As_l[sub*512 + lane*8];
        }
#pragma unroll
        for (int j = 0; j < NI; ++j) {
            const int sub = wn*NI + j;
            fbh[j] = *(const short8*)&Bs_h[sub*512 + lane*8];
            fbl[j] = *(const short8*)&Bs_l[sub*512 + lane*8];
        }
#pragma unroll
        for (int i = 0; i < MI; ++i)
#pragma unroll
            for (int j = 0; j < NI; ++j) {
                acc[i][j] = __builtin_amdgcn_mfma_f32_16x16x32_bf16(fah[i], fbh[j], acc[i][j], 0, 0, 0);
                acc[i][j] = __builtin_amdgcn_mfma_f32_16x16x32_bf16(fah[i], fbl[j], acc[i][j], 0, 0, 0);
                acc[i][j] = __builtin_amdgcn_mfma_f32_16x16x32_bf16(fal[i], fbh[j], acc[i][j], 0, 0, 0);
            }
    }

    const float rs = (EPI == 1) ? rsp[0] : 0.f;
    const int lc = lane >> 4, col = lane & 15;
#pragma unroll
    for (int j = 0; j < NI; ++j) {
        const int n = (n0t + wn*NI + j)*16 + col;
        if (n < Nvalid) {
            const float bv = (EPI != 1 && bias) ? bias[n] : 0.f;
#pragma unroll
            for (int i = 0; i < MI; ++i) {
                const int mb = (m0t + wm*MI + i)*16 + lc*4;
#pragma unroll
                for (int r = 0; r < 4; ++r) {
                    float v = acc[i][j][r];
                    float* cp = C + (size_t)(mb + r)*ldc + n;
                    if (EPI == 0)      *cp = v + bv;
                    else if (EPI == 1) *cp = fmaf(rs, v, *cp);
                    else               *cp = tanhf(v + bv);
                }
            }
        }
    }
}

// ---------------------------------------------------------------------------
// LayerNorm over DM=256 -> blocked bf16 hi/lo (+ optional fp32 row-major)
// ---------------------------------------------------------------------------
template<int WF32>
__global__ __launch_bounds__(256) void ln_blk_k(
    const float* __restrict__ in, const float* __restrict__ g,
    const float* __restrict__ b,
    short* __restrict__ Oh, short* __restrict__ Ol, float* __restrict__ o32)
{
    __shared__ float sT[16][SLN];
    const int tid = threadIdx.x;
    const int row = tid >> 4, c = tid & 15;
    const int m = blockIdx.x*16 + row;
    float v[16];
#pragma unroll
    for (int qq = 0; qq < 4; ++qq)
        *(float4*)&v[qq*4] = *(const float4*)(in + (size_t)m*NDM + c*16 + qq*4);
    float s = 0.f, q = 0.f;
#pragma unroll
    for (int i = 0; i < 16; ++i) { s += v[i]; q += v[i]*v[i]; }
#pragma unroll
    for (int o = 8; o; o >>= 1) { s += __shfl_xor(s, o); q += __shfl_xor(q, o); }
    const float mu = s * (1.f/NDM);
    const float r = rsqrtf(q*(1.f/NDM) - mu*mu + 1e-5f);
#pragma unroll
    for (int i = 0; i < 16; ++i) {
        const int kg = c*16 + i;
        v[i] = (v[i]-mu)*r*g[kg] + b[kg];
        sT[row][kg] = v[i];
    }
    if (WF32) {
#pragma unroll
        for (int qq = 0; qq < 4; ++qq)
            *(float4*)(o32 + (size_t)m*NDM + c*16 + qq*4) = *(const float4*)&v[qq*4];
    }
    __syncthreads();
#pragma unroll
    for (int qv = 0; qv < 2; ++qv) {
        const int slot = tid + 256*qv;
        const int tile = slot >> 6, ln2 = slot & 63;
        const int mr = ln2 & 15, kc = ln2 >> 4;
        float vv[8];
        *(float4*)&vv[0] = *(const float4*)&sT[mr][tile*32 + kc*8];
        *(float4*)&vv[4] = *(const float4*)&sT[mr][tile*32 + kc*8 + 4];
        short8 h8, l8; cvt8(vv, h8, l8);
        const size_t off = ((size_t)blockIdx.x*8 + tile)*512 + ln2*8;
        *(short8*)(Oh + off) = h8;
        *(short8*)(Ol + off) = l8;
    }
}

// ---------------------------------------------------------------------------
// depthwise causal conv(4) + silu -> xc fp32 row-major AND blocked hi/lo
// ---------------------------------------------------------------------------
#define SCV 520
__global__ __launch_bounds__(256) void conv_blk_k(
    const float* __restrict__ xz, const float* __restrict__ cw,
    const float* __restrict__ cb, float* __restrict__ xc32,
    short* __restrict__ Oh, short* __restrict__ Ol)
{
    __shared__ float sT[16][SCV];
    const int tid = threadIdx.x;
    const int row = tid >> 4, cg = tid & 15;
    const int m = blockIdx.x*16 + row;
    const int t = m & (NT-1);
#pragma unroll
    for (int grp = 0; grp < 4; ++grp) {
        const int ch = cg*32 + grp*8;
        float a[8];
        *(float4*)&a[0] = *(const float4*)(cb + ch);
        *(float4*)&a[4] = *(const float4*)(cb + ch + 4);
        float4 wv[8];
#pragma unroll
        for (int i = 0; i < 8; ++i) wv[i] = *(const float4*)(cw + (ch+i)*4);
#pragma unroll
        for (int kk = 0; kk < 4; ++kk) {
            if (t - 3 + kk >= 0) {
                const float* xp = xz + (size_t)(m-3+kk)*(2*NDI) + ch;
                float xv[8];
                *(float4*)&xv[0] = *(const float4*)xp;
                *(float4*)&xv[4] = *(const float4*)(xp + 4);
                const float tap[8] = {
                    kk==0?wv[0].x:kk==1?wv[0].y:kk==2?wv[0].z:wv[0].w,
                    kk==0?wv[1].x:kk==1?wv[1].y:kk==2?wv[1].z:wv[1].w,
                    kk==0?wv[2].x:kk==1?wv[2].y:kk==2?wv[2].z:wv[2].w,
                    kk==0?wv[3].x:kk==1?wv[3].y:kk==2?wv[3].z:wv[3].w,
                    kk==0?wv[4].x:kk==1?wv[4].y:kk==2?wv[4].z:wv[4].w,
                    kk==0?wv[5].x:kk==1?wv[5].y:kk==2?wv[5].z:wv[5].w,
                    kk==0?wv[6].x:kk==1?wv[6].y:kk==2?wv[6].z:wv[6].w,
                    kk==0?wv[7].x:kk==1?wv[7].y:kk==2?wv[7].z:wv[7].w};
#pragma unroll
                for (int i = 0; i < 8; ++i) a[i] = fmaf(xv[i], tap[i], a[i]);
            }
        }
#pragma unroll
        for (int i = 0; i < 8; ++i) a[i] = a[i] / (1.f + __expf(-a[i]));
        *(float4*)&sT[row][ch] = *(const float4*)&a[0];
        *(float4*)&sT[row][ch+4] = *(const float4*)&a[4];
        *(float4*)(xc32 + (size_t)m*NDI + ch) = *(const float4*)&a[0];
        *(float4*)(xc32 + (size_t)m*NDI + ch + 4) = *(const float4*)&a[4];
    }
    __syncthreads();
#pragma unroll
    for (int q = 0; q < 4; ++q) {
        const int slot = tid + 256*q;
        const int tile = slot >> 6, ln2 = slot & 63;
        const int mr = ln2 & 15, kc = ln2 >> 4;
        float vv[8];
        *(float4*)&vv[0] = *(const float4*)&sT[mr][tile*32 + kc*8];
        *(float4*)&vv[4] = *(const float4*)&sT[mr][tile*32 + kc*8 + 4];
        short8 h8, l8; cvt8(vv, h8, l8);
        const size_t off = ((size_t)blockIdx.x*16 + tile)*512 + ln2*8;
        *(short8*)(Oh + off) = h8;
        *(short8*)(Ol + off) = l8;
    }
}

// ---------------------------------------------------------------------------
// selective scan v5 with FUSED dt: block = 64 channels, one b; grid NB*8.
// dt computed in-LDS from staged dbc (wave-broadcast dot + softplus).
// 4 states/thread, DPP quad reduction, x transposed [d][t].
// ---------------------------------------------------------------------------
__global__ __launch_bounds__(256) void scan_k(
    const float* __restrict__ dbc, const float* __restrict__ xcp,
    const float* __restrict__ xz,
    const float* __restrict__ dtw, const float* __restrict__ dtb,
    const float* __restrict__ Alog, const float* __restrict__ Dp,
    short* __restrict__ Yh, short* __restrict__ Yl)
{
    __shared__ float sBC[64][52];   // R[0:16], B[16:32], C[32:48]
    __shared__ float sDt[64][52];   // [t][d]
    __shared__ float sX[64][68];    // [d][t] transposed
    __shared__ float sY[64][68];
    const int tid = threadIdx.x;
    const int w = tid >> 6, lane = tid & 63;
    const int dl = lane >> 2, sg = lane & 3;
    const int b = blockIdx.x >> 3;
    const int d0 = (blockIdx.x & 7) << 4 << 2;   // *64
    const int dloc = w*16 + dl;
    const int d = d0 + dloc;
    float ar[4];
    {
        float4 al4 = *(const float4*)(Alog + d*NDS + sg*4);
        ar[0] = -__expf(al4.x); ar[1] = -__expf(al4.y);
        ar[2] = -__expf(al4.z); ar[3] = -__expf(al4.w);
    }
    const float Dpv = Dp[d];
    // dt params for this thread's dt-channel (lane-mapped)
    const int dldt = lane;
    float wr[16];
#pragma unroll
    for (int r4 = 0; r4 < 4; ++r4)
        *(float4*)&wr[r4*4] = *(const float4*)(dtw + (size_t)(d0 + dldt)*NR + r4*4);
    const float dtbv = dtb[d0 + dldt];

    float hr[4] = {0.f, 0.f, 0.f, 0.f};
    const int mbase = b*NT;

    for (int c0 = 0; c0 < NT; c0 += 64) {
        {   // stage full dbc rows (48 floats): thread (row, q) -> 3 float4
            const int row = tid >> 2, q = tid & 3;
            const float* dp_ = dbc + (size_t)(mbase + c0 + row)*48 + q*12;
            *(float4*)&sBC[row][q*12]     = *(const float4*)dp_;
            *(float4*)&sBC[row][q*12 + 4] = *(const float4*)(dp_ + 4);
            *(float4*)&sBC[row][q*12 + 8] = *(const float4*)(dp_ + 8);
        }
        {   // stage x transposed -> sX[d][t]
            const int tr = tid >> 2, qq = tid & 3;
            const float* xsrc = xcp + (size_t)(mbase + c0 + tr)*NDI + d0 + qq*16;
#pragma unroll
            for (int i = 0; i < 4; ++i) {
                float4 xv = *(const float4*)(xsrc + i*4);
                const int dd = qq*16 + i*4;
                sX[dd+0][tr]=xv.x; sX[dd+1][tr]=xv.y; sX[dd+2][tr]=xv.z; sX[dd+3][tr]=xv.w;
            }
        }
        __syncthreads();
        // ---- fused dt: each thread computes dt for (d0+lane) at 16 t's ----
#pragma unroll
        for (int q = 0; q < 16; ++q) {
            const int t = w + 4*q;
            float a = dtbv;
#pragma unroll
            for (int r4 = 0; r4 < 4; ++r4) {
                const float4 rv = *(const float4*)&sBC[t][r4*4];  // broadcast
                a = fmaf(rv.x, wr[r4*4+0], a);
                a = fmaf(rv.y, wr[r4*4+1], a);
                a = fmaf(rv.z, wr[r4*4+2], a);
                a = fmaf(rv.w, wr[r4*4+3], a);
            }
            sDt[t][dldt] = (a > 20.f) ? a : log1pf(__expf(a));
        }
        __syncthreads();
        // ---- scan: 16 groups x 4 steps, register double-buffered ----
        float4 Bt[2][4], Ct[2][4], x4[2];
        float dts[2][4];
#pragma unroll
        for (int i = 0; i < 4; ++i) {
            Bt[0][i] = *(const float4*)&sBC[i][16 + sg*4];
            Ct[0][i] = *(const float4*)&sBC[i][32 + sg*4];
            dts[0][i] = sDt[i][dloc];
        }
        x4[0] = *(const float4*)&sX[dloc][0];
#pragma unroll
        for (int g = 0; g < 16; ++g) {
            const int cur = g & 1, nxt = cur ^ 1;
            if (g < 15) {
                const int t4 = (g+1)*4;
#pragma unroll
                for (int i = 0; i < 4; ++i) {
                    Bt[nxt][i] = *(const float4*)&sBC[t4+i][16 + sg*4];
                    Ct[nxt][i] = *(const float4*)&sBC[t4+i][32 + sg*4];
                    dts[nxt][i] = sDt[t4+i][dloc];
                }
                x4[nxt] = *(const float4*)&sX[dloc][t4];
            }
#pragma unroll
            for (int i = 0; i < 4; ++i) {
                const float dtv = dts[cur][i];
                const float xv  = (i==0)?x4[cur].x:(i==1)?x4[cur].y:(i==2)?x4[cur].z:x4[cur].w;
                const float4 Bv = Bt[cur][i];
                const float4 Cv = Ct[cur][i];
                const float dbx = dtv * xv;
                float pa0 = __expf(dtv*ar[0]);
                float pa1 = __expf(dtv*ar[1]);
                float pa2 = __expf(dtv*ar[2]);
                float pa3 = __expf(dtv*ar[3]);
                hr[0] = fmaf(pa0, hr[0], dbx*Bv.x);
                hr[1] = fmaf(pa1, hr[1], dbx*Bv.y);
                hr[2] = fmaf(pa2, hr[2], dbx*Bv.z);
                hr[3] = fmaf(pa3, hr[3], dbx*Bv.w);
                float cp = hr[0]*Cv.x;
                cp = fmaf(hr[1], Cv.y, cp);
                cp = fmaf(hr[2], Cv.z, cp);
                cp = fmaf(hr[3], Cv.w, cp);
                cp = quad_sum(cp);
                if (sg == 0) sY[g*4 + i][dloc] = fmaf(Dpv, xv, cp);
            }
        }
        __syncthreads();
        // ---- pack chunk: y * silu(z) -> blocked bf16 ----
#pragma unroll
        for (int q = 0; q < 2; ++q) {
            const int slot = tid + 256*q;
            const int tile = slot >> 6, ln2 = slot & 63;
            const int tm = tile >> 1, tk = tile & 1;
            const int mr = ln2 & 15, kc = ln2 >> 4;
            const int m = mbase + c0 + tm*16 + mr;
            const int kd = d0 + tk*32 + kc*8;
            float yv[8];
            *(float4*)&yv[0] = *(const float4*)&sY[tm*16 + mr][tk*32 + kc*8];
            *(float4*)&yv[4] = *(const float4*)&sY[tm*16 + mr][tk*32 + kc*8 + 4];
            float zv[8];
            *(float4*)&zv[0] = *(const float4*)(xz + (size_t)m*(2*NDI) + NDI + kd);
            *(float4*)&zv[4] = *(const float4*)(xz + (size_t)m*(2*NDI) + NDI + kd + 4);
#pragma unroll
            for (int i = 0; i < 8; ++i)
                yv[i] *= zv[i] / (1.f + __expf(-zv[i]));
            short8 h8, l8; cvt8(yv, h8, l8);
            const size_t off = ((size_t)(m>>4)*16 + (kd>>5))*512 + ln2*8;
            *(short8*)(Yh + off) = h8;
            *(short8*)(Yl + off) = l8;
        }
        __syncthreads();
    }
}

// ---------------------------------------------------------------------------
__global__ __launch_bounds__(64) void score_k(
    const float* __restrict__ t1, const float* __restrict__ w2,
    float* __restrict__ sout)
{
    const int m = blockIdx.x;
    const int lane = threadIdx.x;
    float v = t1[(size_t)m*NH + lane]*w2[lane]
            + t1[(size_t)m*NH + 64 + lane]*w2[64 + lane];
#pragma unroll
    for (int o = 32; o; o >>= 1) v += __shfl_xor(v, o);
    if (lane == 0) sout[m] = v;
}

__global__ __launch_bounds__(256) void pool_k(
    const float* __restrict__ sbuf, const float* __restrict__ u,
    const int* __restrict__ lengths, float* __restrict__ ctx)
{
    __shared__ float al[NT];
    __shared__ float red[256];
    const int b = blockIdx.x;
    const int tid = threadIdx.x;
    const int len = lengths[b];
    float mx = -3.4e38f;
    for (int t = tid; t < len; t += 256) mx = fmaxf(mx, sbuf[b*NT + t]);
    red[tid] = mx; __syncthreads();
    for (int o = 128; o; o >>= 1) { if (tid < o) red[tid] = fmaxf(red[tid], red[tid+o]); __syncthreads(); }
    mx = red[0];
    __syncthreads();
    float sm = 0.f;
    for (int t = tid; t < len; t += 256) {
        float e = __expf(sbuf[b*NT + t] - mx);
        al[t] = e; sm += e;
    }
    red[tid] = sm; __syncthreads();
    for (int o = 128; o; o >>= 1) { if (tid < o) red[tid] += red[tid+o]; __syncthreads(); }
    const float rZ = 1.f / red[0];
    float acc = 0.f;
    const float* up = u + (size_t)b*NT*NDM + tid;
    for (int t = 0; t < len; ++t) acc = fmaf(al[t], up[(size_t)t*NDM], acc);
    ctx[b*NDM + tid] = acc * rZ;
}

__global__ __launch_bounds__(64) void head_k(
    const float* __restrict__ ctx, const float* __restrict__ hw,
    const float* __restrict__ hb, float* __restrict__ o)
{
    const int b = blockIdx.x;
    const int lane = threadIdx.x;
    const float4 c4 = *(const float4*)(ctx + b*NDM + lane*4);
#pragma unroll
    for (int c = 0; c < NNC; ++c) {
        const float4 w4 = *(const float4*)(hw + c*NDM + lane*4);
        float v = c4.x*w4.x + c4.y*w4.y + c4.z*w4.z + c4.w*w4.w;
#pragma unroll
        for (int off = 32; off; off >>= 1) v += __shfl_xor(v, off);
        if (lane == 0) o[b*NNC + c] = v + hb[c];
    }
}

// ---------------------------------------------------------------------------
extern "C" void kernel_launch(void* const* d_in, const int* in_sizes, int n_in,
                              void* d_out, int out_size, void* d_ws, size_t ws_size,
                              hipStream_t stream)
{
    (void)in_sizes; (void)n_in; (void)out_size; (void)ws_size;
    const float* x         = (const float*)d_in[0];
    const int*   lengths   = (const int*)  d_in[1];
    const float* tin_gamma = (const float*)d_in[2];
    const float* tin_beta  = (const float*)d_in[3];
    const float* proj_w    = (const float*)d_in[4];
    const float* proj_b    = (const float*)d_in[5];
    const float* ln_g      = (const float*)d_in[6];
    const float* ln_b      = (const float*)d_in[7];
    const float* in_proj_w = (const float*)d_in[8];
    const float* conv_w    = (const float*)d_in[9];
    const float* conv_b    = (const float*)d_in[10];
    const float* x_proj_w  = (const float*)d_in[11];
    const float* dt_proj_w = (const float*)d_in[12];
    const float* dt_proj_b = (const float*)d_in[13];
    const float* A_log     = (const float*)d_in[14];
    const float* D_param   = (const float*)d_in[15];
    const float* out_proj_w= (const float*)d_in[16];
    const float* out_ln_g  = (const float*)d_in[17];
    const float* out_ln_b  = (const float*)d_in[18];
    const float* res_scale = (const float*)d_in[19];
    const float* attn_w1   = (const float*)d_in[20];
    const float* attn_b1   = (const float*)d_in[21];
    const float* attn_w2   = (const float*)d_in[22];
    const float* head_w    = (const float*)d_in[23];
    const float* head_b    = (const float*)d_in[24];
    float* out = (float*)d_out;

    float* ws = (float*)d_ws;
    float* mean   = ws;                         // 65536
    float* rstd   = mean + 65536;               // 65536
    float* hbuf   = rstd + 65536;               // NM*NDM
    float* ubuf32 = hbuf + (size_t)NM*NDM;      // NM*NDM
    float* dbc    = ubuf32 + (size_t)NM*NDM;    // NM*48
    float* t1     = dbc + (size_t)NM*48;        // NM*NH
    float* sbuf   = t1 + (size_t)NM*NH;         // NM
    float* ctx    = sbuf + NM;                  // NB*NDM
    float* fend   = ctx + NB*NDM;
    short* ublk_h = (short*)fend;
    short* ublk_l = ublk_h + (size_t)NM*NDM;
    short* xcb_h  = ublk_l + (size_t)NM*NDM;
    short* xcb_l  = xcb_h + (size_t)NM*NDI;
    short* yq_h   = xcb_l + (size_t)NM*NDI;
    short* yq_l   = yq_h + (size_t)NM*NDI;
    short* pw_h   = yq_l + (size_t)NM*NDI;
    short* pw_l   = pw_h + (size_t)256*2048;
    short* iw_h   = pw_l + (size_t)256*2048;
    short* iw_l   = iw_h + (size_t)4*1024*256;
    short* xw_h   = iw_l + (size_t)4*1024*256;
    short* xw_l   = xw_h + (size_t)4*64*512;
    short* ow_h   = xw_l + (size_t)4*64*512;
    short* ow_l   = ow_h + (size_t)4*256*512;
    short* aw_h   = ow_l + (size_t)4*256*512;
    short* aw_l   = aw_h + (size_t)128*256;
    float* over   = (float*)(aw_l + (size_t)128*256);
    short* xn_h   = (short*)over;
    short* xn_l   = xn_h + (size_t)NM*ND;
    float* xz     = over;
    float* xc32   = over + (size_t)NM*2*NDI;

    const dim3 blk(256);

    wconv_k<<<dim3(16, 8), blk, 0, stream>>>(proj_w, pw_h, pw_l, 2048, 1<<28, 1<<28);
    wconv_k<<<dim3(256, 1), blk, 0, stream>>>(in_proj_w, iw_h, iw_l, 256, 1<<28, 1<<28);
    wconv_k<<<dim3(16, 2), blk, 0, stream>>>(x_proj_w, xw_h, xw_l, 512, 64, 48);
    wconv_k<<<dim3(64, 2), blk, 0, stream>>>(out_proj_w, ow_h, ow_l, 512, 1<<28, 1<<28);
    wconv_k<<<dim3(8, 1), blk, 0, stream>>>(attn_w1, aw_h, aw_l, 256, 1<<28, 1<<28);

    tin_stats_k<<<dim3(NB*32), blk, 0, stream>>>(x, lengths, mean, rstd);
    tin_norm_k<<<dim3(NM/16, 8), blk, 0, stream>>>(x, lengths, mean, rstd,
        tin_gamma, tin_beta, xn_h, xn_l);
    mgemm_k<8,8,0><<<dim3(NM/128, 2), blk, 0, stream>>>(
        xn_h, xn_l, pw_h, pw_l, proj_b, hbuf, NDM, NDM, 2048, nullptr);

    for (int l = 0; l < NL; ++l) {
        ln_blk_k<0><<<dim3(NM/16), blk, 0, stream>>>(
            hbuf, ln_g + l*NDM, ln_b + l*NDM, ublk_h, ublk_l, nullptr);
        mgemm_k<4,8,0><<<dim3(NM/64, 8), blk, 0, stream>>>(
            ublk_h, ublk_l, iw_h + (size_t)l*1024*256, iw_l + (size_t)l*1024*256,
            nullptr, xz, 2*NDI, 2*NDI, NDM, nullptr);
        conv_blk_k<<<dim3(NM/16), blk, 0, stream>>>(
            xz, conv_w + (size_t)l*NDI*4, conv_b + (size_t)l*NDI, xc32, xcb_h, xcb_l);
        mgemm_k<4,4,0><<<dim3(NM/64, 1), blk, 0, stream>>>(
            xcb_h, xcb_l, xw_h + (size_t)l*64*512, xw_l + (size_t)l*64*512,
            nullptr, dbc, 48, 48, 512, nullptr);
        scan_k<<<dim3(NB*8), blk, 0, stream>>>(
            dbc, xc32, xz, dt_proj_w + (size_t)l*NDI*NR, dt_proj_b + (size_t)l*NDI,
            A_log + (size_t)l*NDI*NDS, D_param + (size_t)l*NDI, yq_h, yq_l);
        mgemm_k<4,8,1><<<dim3(NM/64, 2), blk, 0, stream>>>(
            yq_h, yq_l, ow_h + (size_t)l*256*512, ow_l + (size_t)l*256*512,
            nullptr, hbuf, NDM, NDM, 512, res_scale);
    }

    ln_blk_k<1><<<dim3(NM/16), blk, 0, stream>>>(
        hbuf, out_ln_g, out_ln_b, ublk_h, ublk_l, ubuf32);
    mgemm_k<4,4,2><<<dim3(NM/64, 2), blk, 0, stream>>>(
        ublk_h, ublk_l, aw_h, aw_l, attn_b1, t1, NH, NH, 256, nullptr);
    score_k<<<dim3(NM), dim3(64), 0, stream>>>(t1, attn_w2, sbuf);
    pool_k<<<dim3(NB), blk, 0, stream>>>(sbuf, ubuf32, lengths, ctx);
    head_k<<<dim3(NB), dim3(64), 0, stream>>>(ctx, head_w, head_b, out);
}